// Round 1
// baseline (118.277 us; speedup 1.0000x reference)
//
#include <hip/hip_runtime.h>
#include <cstdint>
#include <cstddef>

typedef unsigned short u16;
typedef __bf16 bf16x8 __attribute__((ext_vector_type(8)));
typedef float f32x4 __attribute__((ext_vector_type(4)));
typedef u16 u16x4 __attribute__((ext_vector_type(4)));
typedef u16 u16x8 __attribute__((ext_vector_type(8)));

#define B_ 16384
#define D_ 64
#define MAXC_ 8
#define NCON_ 2000
#define NCONP_ 2048
#define TDIM_ 1024
#define HID_ 256

__device__ inline u16 f2b(float f){
  unsigned u = __float_as_uint(f);
  u += 0x7fffu + ((u >> 16) & 1u);
  return (u16)(u >> 16);
}
__device__ inline float b2f(u16 u){ return __uint_as_float(((unsigned)u) << 16); }

__device__ inline void gload16(const void* g, void* l){
  __builtin_amdgcn_global_load_lds((const __attribute__((address_space(1))) unsigned*)g,
                                   (__attribute__((address_space(3))) unsigned*)l, 16, 0, 0);
}

__device__ inline float wsum(float v){
  #pragma unroll
  for (int o = 32; o; o >>= 1) v += __shfl_xor(v, o);
  return v;
}

// ---------------- weight prep: transposes + fused GRU weight ----------------
// W1T[256][1024], W2T[64][256], WxhT[256][320] (cols: [r_comb|z_comb|xn|hn]), bxh[256]
__global__ __launch_bounds__(256) void k_prep_w(
    const float* __restrict__ W1, const float* __restrict__ W2,
    const float* __restrict__ Wx, const float* __restrict__ Wh,
    const float* __restrict__ bx, const float* __restrict__ bh,
    u16* __restrict__ W1T, u16* __restrict__ W2T, u16* __restrict__ WxhT,
    float* __restrict__ bxh)
{
  int gid = blockIdx.x * 256 + threadIdx.x;
  if (gid < 262144){                       // W1T: n*1024 + k
    int n = gid >> 10, k = gid & 1023;
    W1T[gid] = f2b(W1[(size_t)k * 256 + n]);
  } else if (gid < 278528){                // W2T: n*256 + k
    int t = gid - 262144;
    int n = t >> 8, k = t & 255;
    W2T[t] = f2b(W2[(size_t)k * 64 + n]);
  } else if (gid < 360448){                // WxhT: j*320 + kk
    int t = gid - 278528;
    int j = t / 320, kk = t % 320;
    float v;
    if (kk < 256){
      v = (j < 192) ? Wx[(size_t)kk * 192 + j] : 0.f;
    } else {
      int kh = kk - 256;
      v = (j < 128) ? Wh[(size_t)kh * 192 + j]
                    : (j >= 192 ? Wh[(size_t)kh * 192 + (j - 64)] : 0.f);
    }
    WxhT[t] = f2b(v);
  } else if (gid < 360704){                // bias: r,z: bx+bh ; xn: bx ; hn: bh
    int j = gid - 360448;
    bxh[j] = (j < 128) ? (bx[j] + bh[j]) : (j < 192 ? bx[j] : bh[j - 64]);
  }
}

// ---------------- concept prep: f32 -> bf16 + norms, zero-pad to 2048 -------
__global__ __launch_bounds__(256) void k_prep_c(const float* __restrict__ con,
                                                u16* __restrict__ cb,
                                                float* __restrict__ cn)
{
  const int lane = threadIdx.x & 63;
  const int r = blockIdx.x * 4 + (threadIdx.x >> 6);
  u16* dst = cb + (size_t)r * TDIM_;
  if (r < NCON_){
    const float* src = con + (size_t)r * TDIM_;
    float ss = 0.f;
    #pragma unroll
    for (int c = 0; c < 4; ++c){
      float4 v = *(const float4*)(src + c * 256 + lane * 4);
      ss += v.x*v.x + v.y*v.y + v.z*v.z + v.w*v.w;
      u16x4 o = { f2b(v.x), f2b(v.y), f2b(v.z), f2b(v.w) };
      *(u16x4*)(dst + c * 256 + lane * 4) = o;
    }
    ss = wsum(ss);
    if (lane == 0) cn[r] = sqrtf(ss);
  } else {
    u16x4 z = { 0, 0, 0, 0 };
    #pragma unroll
    for (int c = 0; c < 4; ++c) *(u16x4*)(dst + c * 256 + lane * 4) = z;
  }
}

// ---------------- gathered-problem prep: gather + bf16 + norms --------------
__global__ __launch_bounds__(256) void k_prep_q(const float* __restrict__ ex,
                                                const int* __restrict__ pid,
                                                u16* __restrict__ qb,
                                                float* __restrict__ qn)
{
  const int lane = threadIdx.x & 63;
  const int b = blockIdx.x * 4 + (threadIdx.x >> 6);
  const float* src = ex + (size_t)pid[b] * TDIM_;
  u16* dst = qb + (size_t)b * TDIM_;
  float ss = 0.f;
  #pragma unroll
  for (int c = 0; c < 4; ++c){
    float4 v = *(const float4*)(src + c * 256 + lane * 4);
    ss += v.x*v.x + v.y*v.y + v.z*v.z + v.w*v.w;
    u16x4 o = { f2b(v.x), f2b(v.y), f2b(v.z), f2b(v.w) };
    *(u16x4*)(dst + c * 256 + lane * 4) = o;
  }
  ss = wsum(ss);
  if (lane == 0) qn[b] = sqrtf(ss);
}

// ---------------- generic bf16 MFMA GEMM: C = A[M,K] @ BT[N,K]^T + bias -----
// BN fixed 64. grid = (M/BM, N/64). LDS linear, source inverse-swizzled,
// reads XOR-swizzled (T2 / rule #21). 4 waves: wave w owns rows [w*BM/4, ...).
template<int BM, int RELU, int WF32, int WB16>
__global__ __launch_bounds__(256) void gemm_k(const u16* __restrict__ A, int lda,
    const u16* __restrict__ BT, int ldb, const float* __restrict__ bias,
    float* __restrict__ Cf, u16* __restrict__ Cb, int ldc, int K)
{
  constexpr int MF = BM / 64;           // 16x16 row-frags per wave
  __shared__ u16 As[BM * 64];
  __shared__ u16 Bs[64 * 64];
  const int tid = threadIdx.x;
  const int lane = tid & 63;
  const int w = tid >> 6;
  const int m0 = blockIdx.x * BM;
  const int n0 = blockIdx.y * 64;
  f32x4 acc[MF][4] = {};
  const int nkt = K >> 6;
  for (int kt = 0; kt < nkt; ++kt){
    #pragma unroll
    for (int i = 0; i < BM / 32; ++i){
      int c = i * 256 + tid;
      int row = c >> 3, sub = c & 7;
      gload16(A + (size_t)(m0 + row) * lda + kt * 64 + ((sub ^ (row & 7)) << 3),
              &As[c * 8]);
    }
    #pragma unroll
    for (int i = 0; i < 2; ++i){
      int c = i * 256 + tid;
      int row = c >> 3, sub = c & 7;
      gload16(BT + (size_t)(n0 + row) * ldb + kt * 64 + ((sub ^ (row & 7)) << 3),
              &Bs[c * 8]);
    }
    __syncthreads();
    #pragma unroll
    for (int ks = 0; ks < 2; ++ks){
      const int kb = ks * 64 + (lane >> 4) * 16;   // byte offset in 128B row
      const int lr = lane & 15;
      bf16x8 af[MF];
      #pragma unroll
      for (int fr = 0; fr < MF; ++fr){
        int row = w * (BM / 4) + fr * 16 + lr;
        af[fr] = *(const bf16x8*)((const char*)As + row * 128 + (kb ^ ((row & 7) << 4)));
      }
      bf16x8 bfr[4];
      #pragma unroll
      for (int fc = 0; fc < 4; ++fc){
        int row = fc * 16 + lr;
        bfr[fc] = *(const bf16x8*)((const char*)Bs + row * 128 + (kb ^ ((row & 7) << 4)));
      }
      #pragma unroll
      for (int fr = 0; fr < MF; ++fr)
        #pragma unroll
        for (int fc = 0; fc < 4; ++fc)
          acc[fr][fc] = __builtin_amdgcn_mfma_f32_16x16x32_bf16(af[fr], bfr[fc],
                                                                acc[fr][fc], 0, 0, 0);
    }
    __syncthreads();
  }
  #pragma unroll
  for (int fr = 0; fr < MF; ++fr){
    #pragma unroll
    for (int fc = 0; fc < 4; ++fc){
      const int col = n0 + fc * 16 + (lane & 15);
      const float bv = bias[col];
      #pragma unroll
      for (int j = 0; j < 4; ++j){
        const int row = m0 + w * (BM / 4) + fr * 16 + (lane >> 4) * 4 + j;
        float v = acc[fr][fc][j] + bv;
        if constexpr (RELU) v = fmaxf(v, 0.f);
        if constexpr (WF32) Cf[(size_t)row * ldc + col] = v;
        if constexpr (WB16) Cb[(size_t)row * ldc + col] = f2b(v);
      }
    }
  }
}

// ---------------- fused middle: cosine -> softmax -> rep/v -> prob -> xh ----
__global__ __launch_bounds__(256) void k_mix(const u16* __restrict__ qb,
    const u16* __restrict__ cb, const float* __restrict__ qn,
    const float* __restrict__ cn, const int* __restrict__ rci,
    const int* __restrict__ filt, const float* __restrict__ redq,
    const float* __restrict__ redc, const float* __restrict__ h,
    const float* __restrict__ emb, const float* __restrict__ op,
    const float* __restrict__ Wp, const float* __restrict__ bp,
    float* __restrict__ prob_out, u16* __restrict__ xh)
{
  const int lane = threadIdx.x & 63;
  const int b = blockIdx.x * 4 + (threadIdx.x >> 6);
  const u16* qrow = qb + (size_t)b * TDIM_;
  u16x8 q0 = *(const u16x8*)(qrow + lane * 8);
  u16x8 q1 = *(const u16x8*)(qrow + 512 + lane * 8);
  int idxm[MAXC_];
  #pragma unroll
  for (int m = 0; m < MAXC_; ++m) idxm[m] = rci[b * MAXC_ + m];
  float dots[MAXC_];
  #pragma unroll
  for (int m = 0; m < MAXC_; ++m){
    const u16* crow = cb + (size_t)idxm[m] * TDIM_;
    u16x8 c0 = *(const u16x8*)(crow + lane * 8);
    u16x8 c1 = *(const u16x8*)(crow + 512 + lane * 8);
    float s = 0.f;
    #pragma unroll
    for (int i = 0; i < 8; ++i) s += b2f(q0[i]) * b2f(c0[i]);
    #pragma unroll
    for (int i = 0; i < 8; ++i) s += b2f(q1[i]) * b2f(c1[i]);
    dots[m] = s;
  }
  #pragma unroll
  for (int o = 32; o; o >>= 1){
    #pragma unroll
    for (int m = 0; m < MAXC_; ++m) dots[m] += __shfl_xor(dots[m], o);
  }
  const float qnb = qn[b];
  float sv[MAXC_]; float mx = -3.0e38f;
  #pragma unroll
  for (int m = 0; m < MAXC_; ++m){
    float dnm = fmaxf(qnb * cn[idxm[m]], 1e-8f);
    float s = (filt[b * MAXC_ + m] == 0) ? -1e9f : dots[m] / dnm;
    sv[m] = s; mx = fmaxf(mx, s);
  }
  float se = 0.f;
  #pragma unroll
  for (int m = 0; m < MAXC_; ++m){ sv[m] = __expf(sv[m] - mx); se += sv[m]; }
  const float inv = 1.f / se;
  float rep = 0.f;
  #pragma unroll
  for (int m = 0; m < MAXC_; ++m) rep += sv[m] * redc[(size_t)idxm[m] * D_ + lane];
  rep *= inv;
  const float v0 = redq[(size_t)b * D_ + lane];
  const float hv = h[(size_t)b * D_ + lane];
  const float e0 = emb[(size_t)b * 128 + lane];
  const float e1 = emb[(size_t)b * 128 + 64 + lane];
  float p = hv * Wp[lane] + v0 * Wp[64 + lane] + rep * Wp[128 + lane]
          + e0 * Wp[192 + lane] + e1 * Wp[256 + lane];
  p = wsum(p);
  if (lane == 0) prob_out[b] = p + bp[0];
  const float o = op[b], om = 1.f - o;
  u16* xr = xh + (size_t)b * 320;
  xr[lane]        = f2b(v0 * o  + e0 * om);
  xr[64 + lane]   = f2b(rep * o + e1 * om);
  xr[128 + lane]  = f2b(v0 * om + e0 * o);
  xr[192 + lane]  = f2b(rep * om + e1 * o);
  xr[256 + lane]  = f2b(hv);
}

// ---------------- GRU gates ----------------
__global__ __launch_bounds__(256) void k_gru(const float* __restrict__ g,
                                             const float* __restrict__ h,
                                             float* __restrict__ outh)
{
  int gid = blockIdx.x * 256 + threadIdx.x;     // B*64 threads
  int b = gid >> 6, d = gid & 63;
  const float* gr = g + (size_t)b * 256;
  float r = 1.f / (1.f + __expf(-gr[d]));
  float z = 1.f / (1.f + __expf(-gr[64 + d]));
  float n = tanhf(gr[128 + d] + r * gr[192 + d]);
  outh[gid] = (1.f - z) * n + z * h[gid];
}

extern "C" void kernel_launch(void* const* d_in, const int* in_sizes, int n_in,
                              void* d_out, int out_size, void* d_ws, size_t ws_size,
                              hipStream_t stream) {
  const int*   prob_ids = (const int*)  d_in[0];
  const int*   rci      = (const int*)  d_in[1];
  const int*   filt     = (const int*)  d_in[2];
  const float* h        = (const float*)d_in[3];
  const float* emb      = (const float*)d_in[4];
  const float* op       = (const float*)d_in[5];
  const float* ex       = (const float*)d_in[6];
  const float* con      = (const float*)d_in[7];
  const float* W1       = (const float*)d_in[8];
  const float* b1       = (const float*)d_in[9];
  const float* W2       = (const float*)d_in[10];
  const float* b2       = (const float*)d_in[11];
  const float* Wp       = (const float*)d_in[12];
  const float* bp       = (const float*)d_in[13];
  const float* Wx       = (const float*)d_in[14];
  const float* Wh       = (const float*)d_in[15];
  const float* bx       = (const float*)d_in[16];
  const float* bh       = (const float*)d_in[17];
  float* out = (float*)d_out;

  char* w = (char*)d_ws;
  size_t off = 0;
  auto alloc = [&](size_t bytes){ size_t o = off; off = (off + bytes + 255) & ~(size_t)255; return o; };
  u16*   qb   = (u16*)  (w + alloc((size_t)B_ * TDIM_ * 2));      // 32 MB
  u16*   cb   = (u16*)  (w + alloc((size_t)NCONP_ * TDIM_ * 2));  // 4 MB
  float* qn   = (float*)(w + alloc((size_t)B_ * 4));
  float* cn   = (float*)(w + alloc((size_t)NCONP_ * 4));
  u16*   hqb  = (u16*)  (w + alloc((size_t)B_ * HID_ * 2));       // 8 MB
  u16*   hcb  = (u16*)  (w + alloc((size_t)NCONP_ * HID_ * 2));
  float* redq = (float*)(w + alloc((size_t)B_ * D_ * 4));         // 4 MB
  float* redc = (float*)(w + alloc((size_t)NCONP_ * D_ * 4));
  u16*   xh   = (u16*)  (w + alloc((size_t)B_ * 320 * 2));        // 10 MB
  u16*   W1T  = (u16*)  (w + alloc((size_t)HID_ * TDIM_ * 2));
  u16*   W2T  = (u16*)  (w + alloc((size_t)D_ * HID_ * 2));
  u16*   WxhT = (u16*)  (w + alloc((size_t)256 * 320 * 2));
  float* bxh  = (float*)(w + alloc((size_t)256 * 4));
  float* g    = (float*)qb;   // alias: qb dead after k_mix, g written after

  k_prep_w<<<1409, 256, 0, stream>>>(W1, W2, Wx, Wh, bx, bh, W1T, W2T, WxhT, bxh);
  k_prep_c<<<NCONP_ / 4, 256, 0, stream>>>(con, cb, cn);
  k_prep_q<<<B_ / 4, 256, 0, stream>>>(ex, prob_ids, qb, qn);

  // layer 1: relu(x@W1+b1) -> bf16
  gemm_k<128, 1, 0, 1><<<dim3(B_ / 128, 4), 256, 0, stream>>>(qb, TDIM_, W1T, TDIM_, b1, nullptr, hqb, HID_, TDIM_);
  gemm_k<128, 1, 0, 1><<<dim3(NCONP_ / 128, 4), 256, 0, stream>>>(cb, TDIM_, W1T, TDIM_, b1, nullptr, hcb, HID_, TDIM_);
  // layer 2: h@W2+b2 -> f32
  gemm_k<64, 0, 1, 0><<<dim3(B_ / 64, 1), 256, 0, stream>>>(hqb, HID_, W2T, HID_, b2, redq, nullptr, D_, HID_);
  gemm_k<64, 0, 1, 0><<<dim3(NCONP_ / 64, 1), 256, 0, stream>>>(hcb, HID_, W2T, HID_, b2, redc, nullptr, D_, HID_);

  k_mix<<<B_ / 4, 256, 0, stream>>>(qb, cb, qn, cn, rci, filt, redq, redc,
                                    h, emb, op, Wp, bp, out, xh);

  // GRU gates GEMM: [B,320] @ [320,256] -> g
  gemm_k<128, 0, 1, 0><<<dim3(B_ / 128, 4), 256, 0, stream>>>(xh, 320, WxhT, 320, bxh, g, nullptr, 256, 320);

  k_gru<<<(B_ * D_) / 256, 256, 0, stream>>>(g, h, out + B_);
}

// Round 2
// 113.114 us; speedup vs baseline: 1.0456x; 1.0456x over previous
//
#include <hip/hip_runtime.h>
#include <cstdint>
#include <cstddef>

typedef unsigned short u16;
typedef __bf16 bf16x8 __attribute__((ext_vector_type(8)));
typedef float f32x4 __attribute__((ext_vector_type(4)));
typedef u16 u16x4 __attribute__((ext_vector_type(4)));
typedef u16 u16x8 __attribute__((ext_vector_type(8)));

#define B_ 16384
#define D_ 64
#define MAXC_ 8
#define NCON_ 2000
#define NCONP_ 2048
#define TDIM_ 1024
#define HID_ 256

__device__ inline u16 f2b(float f){
  unsigned u = __float_as_uint(f);
  u += 0x7fffu + ((u >> 16) & 1u);
  return (u16)(u >> 16);
}
__device__ inline float b2f(u16 u){ return __uint_as_float(((unsigned)u) << 16); }

__device__ inline void gload16(const void* g, void* l){
  __builtin_amdgcn_global_load_lds((const __attribute__((address_space(1))) unsigned*)g,
                                   (__attribute__((address_space(3))) unsigned*)l, 16, 0, 0);
}

__device__ inline float wsum(float v){
  #pragma unroll
  for (int o = 32; o; o >>= 1) v += __shfl_xor(v, o);
  return v;
}

__device__ inline float sigf(float x){ return 1.f / (1.f + __expf(-x)); }

// ---------------- weight prep ----------------
// W1T[256][1024], W2T[64][256], WxhT[256][320] with gate-interleaved columns:
// col c -> gate g=(c>>4)&3, d=(c>>6)*16+(c&15). bxh[256] same order.
__global__ __launch_bounds__(256) void k_prep_w(
    const float* __restrict__ W1, const float* __restrict__ W2,
    const float* __restrict__ Wx, const float* __restrict__ Wh,
    const float* __restrict__ bx, const float* __restrict__ bh,
    u16* __restrict__ W1T, u16* __restrict__ W2T, u16* __restrict__ WxhT,
    float* __restrict__ bxh)
{
  int gid = blockIdx.x * 256 + threadIdx.x;
  if (gid < 262144){                       // W1T: n*1024 + k
    int n = gid >> 10, k = gid & 1023;
    W1T[gid] = f2b(W1[(size_t)k * 256 + n]);
  } else if (gid < 278528){                // W2T: n*256 + k
    int t = gid - 262144;
    int n = t >> 8, k = t & 255;
    W2T[t] = f2b(W2[(size_t)k * 64 + n]);
  } else if (gid < 360448){                // WxhT: c*320 + k
    int t = gid - 278528;
    int c = t / 320, k = t % 320;
    int g = (c >> 4) & 3;
    int d = (c >> 6) * 16 + (c & 15);
    float v = 0.f;
    if (k < 256){
      if (g == 0)      v = Wx[(size_t)k * 192 + d];
      else if (g == 1) v = Wx[(size_t)k * 192 + 64 + d];
      else if (g == 2) v = Wx[(size_t)k * 192 + 128 + d];
    } else {
      int kh = k - 256;
      if (g == 0)      v = Wh[(size_t)kh * 192 + d];
      else if (g == 1) v = Wh[(size_t)kh * 192 + 64 + d];
      else if (g == 3) v = Wh[(size_t)kh * 192 + 128 + d];
    }
    WxhT[t] = f2b(v);
  } else if (gid < 360704){                // bxh
    int c = gid - 360448;
    int g = (c >> 4) & 3;
    int d = (c >> 6) * 16 + (c & 15);
    float v;
    if (g == 0)      v = bx[d] + bh[d];
    else if (g == 1) v = bx[64 + d] + bh[64 + d];
    else if (g == 2) v = bx[128 + d];
    else             v = bh[128 + d];
    bxh[c] = v;
  }
}

// ---------------- concept prep: f32 -> bf16 + norms, zero-pad to 2048 -------
__global__ __launch_bounds__(256) void k_prep_c(const float* __restrict__ con,
                                                u16* __restrict__ cb,
                                                float* __restrict__ cn)
{
  const int lane = threadIdx.x & 63;
  const int r = blockIdx.x * 4 + (threadIdx.x >> 6);
  u16* dst = cb + (size_t)r * TDIM_;
  if (r < NCON_){
    const float* src = con + (size_t)r * TDIM_;
    float ss = 0.f;
    #pragma unroll
    for (int c = 0; c < 4; ++c){
      float4 v = *(const float4*)(src + c * 256 + lane * 4);
      ss += v.x*v.x + v.y*v.y + v.z*v.z + v.w*v.w;
      u16x4 o = { f2b(v.x), f2b(v.y), f2b(v.z), f2b(v.w) };
      *(u16x4*)(dst + c * 256 + lane * 4) = o;
    }
    ss = wsum(ss);
    if (lane == 0) cn[r] = sqrtf(ss);
  } else {
    u16x4 z = { 0, 0, 0, 0 };
    #pragma unroll
    for (int c = 0; c < 4; ++c) *(u16x4*)(dst + c * 256 + lane * 4) = z;
  }
}

// ---------------- gathered-problem prep: gather + bf16 + norms --------------
__global__ __launch_bounds__(256) void k_prep_q(const float* __restrict__ ex,
                                                const int* __restrict__ pid,
                                                u16* __restrict__ qb,
                                                float* __restrict__ qn)
{
  const int lane = threadIdx.x & 63;
  const int b = blockIdx.x * 4 + (threadIdx.x >> 6);
  const float* src = ex + (size_t)pid[b] * TDIM_;
  u16* dst = qb + (size_t)b * TDIM_;
  float ss = 0.f;
  #pragma unroll
  for (int c = 0; c < 4; ++c){
    float4 v = *(const float4*)(src + c * 256 + lane * 4);
    ss += v.x*v.x + v.y*v.y + v.z*v.z + v.w*v.w;
    u16x4 o = { f2b(v.x), f2b(v.y), f2b(v.z), f2b(v.w) };
    *(u16x4*)(dst + c * 256 + lane * 4) = o;
  }
  ss = wsum(ss);
  if (lane == 0) qn[b] = sqrtf(ss);
}

// ---------------- fused MLP: red = relu(A@W1+b1)@W2+b2 ----------------------
// BM=64, BN=256 (full hidden), 512 threads / 8 waves. Layer-1 wave tile:
// rows rf*32..+31 (rf=w&1), cols ch*64..+63 (ch=w>>1). Hidden kept in LDS
// (bf16, XOR-swizzled), layer 2 (K=256 -> 64 cols) fused in-block.
__global__ __launch_bounds__(512) void k_mlp(const u16* __restrict__ A,
    const u16* __restrict__ W1T, const float* __restrict__ b1,
    const u16* __restrict__ W2T, const float* __restrict__ b2,
    float* __restrict__ outp)
{
  __shared__ u16 As[64 * 64];     // 8 KB
  __shared__ u16 Bs[256 * 64];    // 32 KB
  __shared__ u16 Hs[64 * 256];    // 32 KB
  const int tid = threadIdx.x;
  const int lane = tid & 63;
  const int w = tid >> 6;
  const int lr = lane & 15;
  const int lq = lane >> 4;
  const int m0 = blockIdx.x * 64;
  const int rf = w & 1, ch = w >> 1;
  const int rf2 = w & 3, cp = w >> 2;

  // preload W2T fragments for layer 2 (L2-hot, latency hidden under K-loop)
  bf16x8 w2f[8][2];
  #pragma unroll
  for (int ks2 = 0; ks2 < 8; ++ks2)
    #pragma unroll
    for (int t = 0; t < 2; ++t){
      int row64 = (cp * 2 + t) * 16 + lr;
      w2f[ks2][t] = *(const bf16x8*)(W2T + (size_t)row64 * 256 + ks2 * 32 + lq * 8);
    }

  f32x4 acc[2][4] = {};
  for (int kt = 0; kt < 16; ++kt){
    {
      int c = tid;
      int row = c >> 3, sub = c & 7;
      gload16(A + (size_t)(m0 + row) * 1024 + kt * 64 + ((sub ^ (row & 7)) << 3), &As[c * 8]);
    }
    #pragma unroll
    for (int i = 0; i < 4; ++i){
      int c = i * 512 + tid;
      int row = c >> 3, sub = c & 7;
      gload16(W1T + (size_t)row * 1024 + kt * 64 + ((sub ^ (row & 7)) << 3), &Bs[c * 8]);
    }
    __syncthreads();
    #pragma unroll
    for (int ks = 0; ks < 2; ++ks){
      const int kb = ks * 64 + lq * 16;
      bf16x8 af[2], bfr[4];
      #pragma unroll
      for (int fr = 0; fr < 2; ++fr){
        int row = rf * 32 + fr * 16 + lr;
        af[fr] = *(const bf16x8*)((const char*)As + row * 128 + (kb ^ ((row & 7) << 4)));
      }
      #pragma unroll
      for (int fc = 0; fc < 4; ++fc){
        int row = ch * 64 + fc * 16 + lr;
        bfr[fc] = *(const bf16x8*)((const char*)Bs + row * 128 + (kb ^ ((row & 7) << 4)));
      }
      #pragma unroll
      for (int fr = 0; fr < 2; ++fr)
        #pragma unroll
        for (int fc = 0; fc < 4; ++fc)
          acc[fr][fc] = __builtin_amdgcn_mfma_f32_16x16x32_bf16(af[fr], bfr[fc],
                                                                acc[fr][fc], 0, 0, 0);
    }
    __syncthreads();
  }
  // hidden -> LDS (bias + relu + bf16), swizzled
  #pragma unroll
  for (int fr = 0; fr < 2; ++fr)
    #pragma unroll
    for (int fc = 0; fc < 4; ++fc){
      int col = ch * 64 + fc * 16 + lr;
      float bv = b1[col];
      #pragma unroll
      for (int j = 0; j < 4; ++j){
        int row = rf * 32 + fr * 16 + lq * 4 + j;
        float v = fmaxf(acc[fr][fc][j] + bv, 0.f);
        *(u16*)((char*)Hs + row * 512 + ((col * 2) ^ ((row & 7) << 4))) = f2b(v);
      }
    }
  __syncthreads();
  // layer 2: [64,256] @ W2T[64,256]^T
  f32x4 acc2[2] = {};
  #pragma unroll
  for (int ks2 = 0; ks2 < 8; ++ks2){
    int row = rf2 * 16 + lr;
    int kb2 = ks2 * 64 + lq * 16;
    bf16x8 af2 = *(const bf16x8*)((const char*)Hs + row * 512 + (kb2 ^ ((row & 7) << 4)));
    #pragma unroll
    for (int t = 0; t < 2; ++t)
      acc2[t] = __builtin_amdgcn_mfma_f32_16x16x32_bf16(af2, w2f[ks2][t], acc2[t], 0, 0, 0);
  }
  #pragma unroll
  for (int t = 0; t < 2; ++t){
    int col = (cp * 2 + t) * 16 + lr;
    float bv = b2[col];
    #pragma unroll
    for (int j = 0; j < 4; ++j){
      int row = m0 + rf2 * 16 + lq * 4 + j;
      outp[(size_t)row * 64 + col] = acc2[t][j] + bv;
    }
  }
}

// ---------------- fused middle: cosine -> softmax -> rep/v -> prob -> xh ----
__global__ __launch_bounds__(256) void k_mix(const u16* __restrict__ qb,
    const u16* __restrict__ cb, const float* __restrict__ qn,
    const float* __restrict__ cn, const int* __restrict__ rci,
    const int* __restrict__ filt, const float* __restrict__ redq,
    const float* __restrict__ redc, const float* __restrict__ h,
    const float* __restrict__ emb, const float* __restrict__ op,
    const float* __restrict__ Wp, const float* __restrict__ bp,
    float* __restrict__ prob_out, u16* __restrict__ xh)
{
  const int lane = threadIdx.x & 63;
  const int b = blockIdx.x * 4 + (threadIdx.x >> 6);
  const u16* qrow = qb + (size_t)b * TDIM_;
  u16x8 q0 = *(const u16x8*)(qrow + lane * 8);
  u16x8 q1 = *(const u16x8*)(qrow + 512 + lane * 8);
  int idxm[MAXC_];
  #pragma unroll
  for (int m = 0; m < MAXC_; ++m) idxm[m] = rci[b * MAXC_ + m];
  float dots[MAXC_];
  #pragma unroll
  for (int m = 0; m < MAXC_; ++m){
    const u16* crow = cb + (size_t)idxm[m] * TDIM_;
    u16x8 c0 = *(const u16x8*)(crow + lane * 8);
    u16x8 c1 = *(const u16x8*)(crow + 512 + lane * 8);
    float s = 0.f;
    #pragma unroll
    for (int i = 0; i < 8; ++i) s += b2f(q0[i]) * b2f(c0[i]);
    #pragma unroll
    for (int i = 0; i < 8; ++i) s += b2f(q1[i]) * b2f(c1[i]);
    dots[m] = s;
  }
  #pragma unroll
  for (int o = 32; o; o >>= 1){
    #pragma unroll
    for (int m = 0; m < MAXC_; ++m) dots[m] += __shfl_xor(dots[m], o);
  }
  const float qnb = qn[b];
  float sv[MAXC_]; float mx = -3.0e38f;
  #pragma unroll
  for (int m = 0; m < MAXC_; ++m){
    float dnm = fmaxf(qnb * cn[idxm[m]], 1e-8f);
    float s = (filt[b * MAXC_ + m] == 0) ? -1e9f : dots[m] / dnm;
    sv[m] = s; mx = fmaxf(mx, s);
  }
  float se = 0.f;
  #pragma unroll
  for (int m = 0; m < MAXC_; ++m){ sv[m] = __expf(sv[m] - mx); se += sv[m]; }
  const float inv = 1.f / se;
  float rep = 0.f;
  #pragma unroll
  for (int m = 0; m < MAXC_; ++m) rep += sv[m] * redc[(size_t)idxm[m] * D_ + lane];
  rep *= inv;
  const float v0 = redq[(size_t)b * D_ + lane];
  const float hv = h[(size_t)b * D_ + lane];
  const float e0 = emb[(size_t)b * 128 + lane];
  const float e1 = emb[(size_t)b * 128 + 64 + lane];
  float p = hv * Wp[lane] + v0 * Wp[64 + lane] + rep * Wp[128 + lane]
          + e0 * Wp[192 + lane] + e1 * Wp[256 + lane];
  p = wsum(p);
  if (lane == 0) prob_out[b] = p + bp[0];
  const float o = op[b], om = 1.f - o;
  u16* xr = xh + (size_t)b * 320;
  xr[lane]        = f2b(v0 * o  + e0 * om);
  xr[64 + lane]   = f2b(rep * o + e1 * om);
  xr[128 + lane]  = f2b(v0 * om + e0 * o);
  xr[192 + lane]  = f2b(rep * om + e1 * o);
  xr[256 + lane]  = f2b(hv);
}

// ---------------- fused GRU: gates GEMM [B,320]@[320,256] + gate math -------
// BM=64, BN=256, 512 threads. Gate-interleaved columns: wave (ch) owns d =
// ch*16+lr with all 4 gates at fc=0..3 -> epilogue entirely in-lane.
__global__ __launch_bounds__(512) void k_gru_gemm(const u16* __restrict__ xh,
    const u16* __restrict__ WxhT, const float* __restrict__ bxh,
    const float* __restrict__ h, float* __restrict__ outh)
{
  __shared__ u16 As[64 * 64];
  __shared__ u16 Bs[256 * 64];
  const int tid = threadIdx.x;
  const int lane = tid & 63;
  const int w = tid >> 6;
  const int lr = lane & 15;
  const int lq = lane >> 4;
  const int m0 = blockIdx.x * 64;
  const int rf = w & 1, ch = w >> 1;
  f32x4 acc[2][4] = {};
  for (int kt = 0; kt < 5; ++kt){
    {
      int c = tid;
      int row = c >> 3, sub = c & 7;
      gload16(xh + (size_t)(m0 + row) * 320 + kt * 64 + ((sub ^ (row & 7)) << 3), &As[c * 8]);
    }
    #pragma unroll
    for (int i = 0; i < 4; ++i){
      int c = i * 512 + tid;
      int row = c >> 3, sub = c & 7;
      gload16(WxhT + (size_t)row * 320 + kt * 64 + ((sub ^ (row & 7)) << 3), &Bs[c * 8]);
    }
    __syncthreads();
    #pragma unroll
    for (int ks = 0; ks < 2; ++ks){
      const int kb = ks * 64 + lq * 16;
      bf16x8 af[2], bfr[4];
      #pragma unroll
      for (int fr = 0; fr < 2; ++fr){
        int row = rf * 32 + fr * 16 + lr;
        af[fr] = *(const bf16x8*)((const char*)As + row * 128 + (kb ^ ((row & 7) << 4)));
      }
      #pragma unroll
      for (int fc = 0; fc < 4; ++fc){
        int row = ch * 64 + fc * 16 + lr;
        bfr[fc] = *(const bf16x8*)((const char*)Bs + row * 128 + (kb ^ ((row & 7) << 4)));
      }
      #pragma unroll
      for (int fr = 0; fr < 2; ++fr)
        #pragma unroll
        for (int fc = 0; fc < 4; ++fc)
          acc[fr][fc] = __builtin_amdgcn_mfma_f32_16x16x32_bf16(af[fr], bfr[fc],
                                                                acc[fr][fc], 0, 0, 0);
    }
    __syncthreads();
  }
  const int d = ch * 16 + lr;
  float bg[4];
  #pragma unroll
  for (int g = 0; g < 4; ++g) bg[g] = bxh[ch * 64 + g * 16 + lr];
  #pragma unroll
  for (int fr = 0; fr < 2; ++fr){
    #pragma unroll
    for (int j = 0; j < 4; ++j){
      float rv = sigf(acc[fr][0][j] + bg[0]);
      float zv = sigf(acc[fr][1][j] + bg[1]);
      float nv = tanhf(acc[fr][2][j] + bg[2] + rv * (acc[fr][3][j] + bg[3]));
      int row = m0 + rf * 32 + fr * 16 + lq * 4 + j;
      float hv = h[(size_t)row * 64 + d];
      outh[(size_t)row * 64 + d] = (1.f - zv) * nv + zv * hv;
    }
  }
}

extern "C" void kernel_launch(void* const* d_in, const int* in_sizes, int n_in,
                              void* d_out, int out_size, void* d_ws, size_t ws_size,
                              hipStream_t stream) {
  const int*   prob_ids = (const int*)  d_in[0];
  const int*   rci      = (const int*)  d_in[1];
  const int*   filt     = (const int*)  d_in[2];
  const float* h        = (const float*)d_in[3];
  const float* emb      = (const float*)d_in[4];
  const float* op       = (const float*)d_in[5];
  const float* ex       = (const float*)d_in[6];
  const float* con      = (const float*)d_in[7];
  const float* W1       = (const float*)d_in[8];
  const float* b1       = (const float*)d_in[9];
  const float* W2       = (const float*)d_in[10];
  const float* b2       = (const float*)d_in[11];
  const float* Wp       = (const float*)d_in[12];
  const float* bp       = (const float*)d_in[13];
  const float* Wx       = (const float*)d_in[14];
  const float* Wh       = (const float*)d_in[15];
  const float* bx       = (const float*)d_in[16];
  const float* bh       = (const float*)d_in[17];
  float* out = (float*)d_out;

  char* w = (char*)d_ws;
  size_t off = 0;
  auto alloc = [&](size_t bytes){ size_t o = off; off = (off + bytes + 255) & ~(size_t)255; return o; };
  u16*   qb   = (u16*)  (w + alloc((size_t)B_ * TDIM_ * 2));      // 32 MB
  u16*   cb   = (u16*)  (w + alloc((size_t)NCONP_ * TDIM_ * 2));  // 4 MB
  float* qn   = (float*)(w + alloc((size_t)B_ * 4));
  float* cn   = (float*)(w + alloc((size_t)NCONP_ * 4));
  float* redq = (float*)(w + alloc((size_t)B_ * D_ * 4));         // 4 MB
  float* redc = (float*)(w + alloc((size_t)NCONP_ * D_ * 4));
  u16*   xh   = (u16*)  (w + alloc((size_t)B_ * 320 * 2));        // 10 MB
  u16*   W1T  = (u16*)  (w + alloc((size_t)HID_ * TDIM_ * 2));
  u16*   W2T  = (u16*)  (w + alloc((size_t)D_ * HID_ * 2));
  u16*   WxhT = (u16*)  (w + alloc((size_t)256 * 320 * 2));
  float* bxh  = (float*)(w + alloc((size_t)256 * 4));

  k_prep_w<<<1409, 256, 0, stream>>>(W1, W2, Wx, Wh, bx, bh, W1T, W2T, WxhT, bxh);
  k_prep_c<<<NCONP_ / 4, 256, 0, stream>>>(con, cb, cn);
  k_prep_q<<<B_ / 4, 256, 0, stream>>>(ex, prob_ids, qb, qn);

  k_mlp<<<B_ / 64, 512, 0, stream>>>(qb, W1T, b1, W2T, b2, redq);
  k_mlp<<<NCONP_ / 64, 512, 0, stream>>>(cb, W1T, b1, W2T, b2, redc);

  k_mix<<<B_ / 4, 256, 0, stream>>>(qb, cb, qn, cn, rci, filt, redq, redc,
                                    h, emb, op, Wp, bp, out, xh);

  k_gru_gemm<<<B_ / 64, 512, 0, stream>>>(xh, WxhT, bxh, h, out + B_);
}

// Round 3
// 110.270 us; speedup vs baseline: 1.0726x; 1.0258x over previous
//
#include <hip/hip_runtime.h>
#include <cstdint>
#include <cstddef>

typedef unsigned short u16;
typedef __bf16 bf16x8 __attribute__((ext_vector_type(8)));
typedef float f32x4 __attribute__((ext_vector_type(4)));
typedef u16 u16x4 __attribute__((ext_vector_type(4)));
typedef u16 u16x8 __attribute__((ext_vector_type(8)));

#define B_ 16384
#define D_ 64
#define MAXC_ 8
#define NCON_ 2000
#define NCONP_ 2048
#define TDIM_ 1024
#define HID_ 256

#define VMW(n) asm volatile("s_waitcnt vmcnt(" #n ")" ::: "memory")
#define LGKM0 asm volatile("s_waitcnt lgkmcnt(0)" ::: "memory")
#define BAR() __builtin_amdgcn_s_barrier()

__device__ inline u16 f2b(float f){
  unsigned u = __float_as_uint(f);
  u += 0x7fffu + ((u >> 16) & 1u);
  return (u16)(u >> 16);
}
__device__ inline float b2f(u16 u){ return __uint_as_float(((unsigned)u) << 16); }

__device__ inline void gload16(const void* g, void* l){
  __builtin_amdgcn_global_load_lds((const __attribute__((address_space(1))) unsigned*)g,
                                   (__attribute__((address_space(3))) unsigned*)l, 16, 0, 0);
}

__device__ inline float wsum(float v){
  #pragma unroll
  for (int o = 32; o; o >>= 1) v += __shfl_xor(v, o);
  return v;
}
__device__ inline float sigf(float x){ return 1.f / (1.f + __expf(-x)); }

// =================== k_prep: gather+convert+norms + weight prep =============
// grid sections: [0,4096) q-gather, [4096,4608) concepts, [4608,6017) weights
__global__ __launch_bounds__(256) void k_prep(
    const float* __restrict__ ex, const int* __restrict__ pid,
    const float* __restrict__ con,
    const float* __restrict__ W1, const float* __restrict__ W2,
    const float* __restrict__ Wx, const float* __restrict__ Wh,
    const float* __restrict__ bx, const float* __restrict__ bh,
    u16* __restrict__ qb, float* __restrict__ qn,
    u16* __restrict__ cb, float* __restrict__ cn,
    u16* __restrict__ W1T, u16* __restrict__ W2T, u16* __restrict__ WxhT,
    float* __restrict__ bxh)
{
  const int bid = blockIdx.x, tid = threadIdx.x;
  const int lane = tid & 63;
  if (bid < 4096){                                  // ---- q gather ----
    const int b = bid * 4 + (tid >> 6);
    const float* src = ex + (size_t)pid[b] * TDIM_;
    u16* dst = qb + (size_t)b * TDIM_;
    float ss = 0.f;
    #pragma unroll
    for (int c = 0; c < 4; ++c){
      float4 v = *(const float4*)(src + c * 256 + lane * 4);
      ss += v.x*v.x + v.y*v.y + v.z*v.z + v.w*v.w;
      u16x4 o = { f2b(v.x), f2b(v.y), f2b(v.z), f2b(v.w) };
      *(u16x4*)(dst + c * 256 + lane * 4) = o;
    }
    ss = wsum(ss);
    if (lane == 0) qn[b] = sqrtf(ss);
  } else if (bid < 4608){                           // ---- concepts ----
    const int r = (bid - 4096) * 4 + (tid >> 6);
    u16* dst = cb + (size_t)r * TDIM_;
    if (r < NCON_){
      const float* src = con + (size_t)r * TDIM_;
      float ss = 0.f;
      #pragma unroll
      for (int c = 0; c < 4; ++c){
        float4 v = *(const float4*)(src + c * 256 + lane * 4);
        ss += v.x*v.x + v.y*v.y + v.z*v.z + v.w*v.w;
        u16x4 o = { f2b(v.x), f2b(v.y), f2b(v.z), f2b(v.w) };
        *(u16x4*)(dst + c * 256 + lane * 4) = o;
      }
      ss = wsum(ss);
      if (lane == 0) cn[r] = sqrtf(ss);
    } else {
      u16x4 z = { 0, 0, 0, 0 };
      #pragma unroll
      for (int c = 0; c < 4; ++c) *(u16x4*)(dst + c * 256 + lane * 4) = z;
    }
  } else {                                          // ---- weights ----
    int gid = (bid - 4608) * 256 + tid;
    if (gid < 262144){                       // W1T: n*1024 + k
      int n = gid >> 10, k = gid & 1023;
      W1T[gid] = f2b(W1[(size_t)k * 256 + n]);
    } else if (gid < 278528){                // W2T: n*256 + k
      int t = gid - 262144;
      int n = t >> 8, k = t & 255;
      W2T[t] = f2b(W2[(size_t)k * 64 + n]);
    } else if (gid < 360448){                // WxhT: c*320 + k, gate-interleaved
      int t = gid - 278528;
      int c = t / 320, k = t % 320;
      int g = (c >> 4) & 3;
      int d = (c >> 6) * 16 + (c & 15);
      float v = 0.f;
      if (k < 256){
        if (g == 0)      v = Wx[(size_t)k * 192 + d];
        else if (g == 1) v = Wx[(size_t)k * 192 + 64 + d];
        else if (g == 2) v = Wx[(size_t)k * 192 + 128 + d];
      } else {
        int kh = k - 256;
        if (g == 0)      v = Wh[(size_t)kh * 192 + d];
        else if (g == 1) v = Wh[(size_t)kh * 192 + 64 + d];
        else if (g == 3) v = Wh[(size_t)kh * 192 + 128 + d];
      }
      WxhT[t] = f2b(v);
    } else if (gid < 360704){                // bxh
      int c = gid - 360448;
      int g = (c >> 4) & 3;
      int d = (c >> 6) * 16 + (c & 15);
      float v;
      if (g == 0)      v = bx[d] + bh[d];
      else if (g == 1) v = bx[64 + d] + bh[64 + d];
      else if (g == 2) v = bx[128 + d];
      else             v = bh[128 + d];
      bxh[c] = v;
    }
  }
}

// =================== k_mlp: red = relu(A@W1+b1)@W2+b2, 2-phase dbuf =========
// blocks [0,256): q-side, [256,288): c-side. BM=64, BN=256, 512 thr / 8 waves.
__global__ __launch_bounds__(512) void k_mlp(const u16* __restrict__ qb,
    const u16* __restrict__ cb, const u16* __restrict__ W1T,
    const float* __restrict__ b1, const u16* __restrict__ W2T,
    const float* __restrict__ b2, float* __restrict__ redq,
    float* __restrict__ redc)
{
  __shared__ u16 As[2][64 * 64];     // 16 KB
  __shared__ u16 Bs[2][256 * 64];    // 64 KB
  __shared__ u16 Hs[64 * 256];       // 32 KB
  const int tid = threadIdx.x;
  const int lane = tid & 63;
  const int w = tid >> 6;
  const int lr = lane & 15, lq = lane >> 4;
  const u16* Abase; float* Obase; int m0;
  if (blockIdx.x < 256){ Abase = qb; Obase = redq; m0 = blockIdx.x << 6; }
  else                 { Abase = cb; Obase = redc; m0 = (blockIdx.x - 256) << 6; }
  const int rf = w & 1, ch = w >> 1;
  const int rf2 = w & 3, cp = w >> 2;

  // preload layer-2 weight fragments (L2-hot; counted-vmcnt analysis safe)
  bf16x8 w2f[8][2];
  #pragma unroll
  for (int ks2 = 0; ks2 < 8; ++ks2)
    #pragma unroll
    for (int t = 0; t < 2; ++t){
      int row64 = (cp * 2 + t) * 16 + lr;
      w2f[ks2][t] = *(const bf16x8*)(W2T + (size_t)row64 * 256 + ks2 * 32 + lq * 8);
    }

  const int arow = tid >> 3, asub = tid & 7;
  auto stage = [&](int buf, int kt){
    gload16(Abase + (size_t)(m0 + arow) * 1024 + kt * 64 + ((asub ^ (arow & 7)) << 3),
            &As[buf][tid * 8]);
    #pragma unroll
    for (int i = 0; i < 4; ++i){
      int cc = i * 512 + tid;
      int r2 = cc >> 3, s2 = cc & 7;
      gload16(W1T + (size_t)r2 * 1024 + kt * 64 + ((s2 ^ (r2 & 7)) << 3),
              &Bs[buf][cc * 8]);
    }
  };

  f32x4 acc[2][4] = {};
  stage(0, 0);
  int cur = 0;
  for (int kt = 0; kt < 16; ++kt){
    if (kt < 15){ stage(cur ^ 1, kt + 1); VMW(5); }
    else        { VMW(0); }
    BAR();
    #pragma unroll
    for (int ks = 0; ks < 2; ++ks){
      const int kb = ks * 64 + lq * 16;
      bf16x8 af[2], bfr[4];
      #pragma unroll
      for (int fr = 0; fr < 2; ++fr){
        int row = rf * 32 + fr * 16 + lr;
        af[fr] = *(const bf16x8*)((const char*)As[cur] + row * 128 + (kb ^ ((row & 7) << 4)));
      }
      #pragma unroll
      for (int fc = 0; fc < 4; ++fc){
        int row = ch * 64 + fc * 16 + lr;
        bfr[fc] = *(const bf16x8*)((const char*)Bs[cur] + row * 128 + (kb ^ ((row & 7) << 4)));
      }
      #pragma unroll
      for (int fr = 0; fr < 2; ++fr)
        #pragma unroll
        for (int fc = 0; fc < 4; ++fc)
          acc[fr][fc] = __builtin_amdgcn_mfma_f32_16x16x32_bf16(af[fr], bfr[fc],
                                                                acc[fr][fc], 0, 0, 0);
    }
    BAR();
    cur ^= 1;
  }
  // hidden -> LDS (bias + relu + bf16), swizzled
  #pragma unroll
  for (int fr = 0; fr < 2; ++fr)
    #pragma unroll
    for (int fc = 0; fc < 4; ++fc){
      int col = ch * 64 + fc * 16 + lr;
      float bv = b1[col];
      #pragma unroll
      for (int j = 0; j < 4; ++j){
        int row = rf * 32 + fr * 16 + lq * 4 + j;
        float v = fmaxf(acc[fr][fc][j] + bv, 0.f);
        *(u16*)((char*)Hs + row * 512 + ((col * 2) ^ ((row & 7) << 4))) = f2b(v);
      }
    }
  __syncthreads();
  // layer 2: [64,256] @ W2T[64,256]^T
  f32x4 acc2[2] = {};
  #pragma unroll
  for (int ks2 = 0; ks2 < 8; ++ks2){
    int row = rf2 * 16 + lr;
    int kb2 = ks2 * 64 + lq * 16;
    bf16x8 af2 = *(const bf16x8*)((const char*)Hs + row * 512 + (kb2 ^ ((row & 7) << 4)));
    #pragma unroll
    for (int t = 0; t < 2; ++t)
      acc2[t] = __builtin_amdgcn_mfma_f32_16x16x32_bf16(af2, w2f[ks2][t], acc2[t], 0, 0, 0);
  }
  #pragma unroll
  for (int t = 0; t < 2; ++t){
    int col = (cp * 2 + t) * 16 + lr;
    float bv = b2[col];
    #pragma unroll
    for (int j = 0; j < 4; ++j){
      int row = m0 + rf2 * 16 + lq * 4 + j;
      Obase[(size_t)row * 64 + col] = acc2[t][j] + bv;
    }
  }
}

// =================== k_mixgru: cosine/softmax/pred + GRU GEMM (xh in LDS) ===
// 256 blocks x 512 thr. Mix phase: wave w owns rows [w*8, w*8+8). Then
// gates GEMM [64,320]@WxhT^T with A from swizzled LDS, B 2-phase staged.
__global__ __launch_bounds__(512) void k_mixgru(
    const u16* __restrict__ qb, const u16* __restrict__ cb,
    const float* __restrict__ qn, const float* __restrict__ cn,
    const int* __restrict__ rci, const int* __restrict__ filt,
    const float* __restrict__ redq, const float* __restrict__ redc,
    const float* __restrict__ h, const float* __restrict__ emb,
    const float* __restrict__ op, const float* __restrict__ Wp,
    const float* __restrict__ bp, const u16* __restrict__ WxhT,
    const float* __restrict__ bxh, float* __restrict__ prob_out,
    float* __restrict__ outh)
{
  __shared__ u16 XH[64 * 320];       // 40 KB, row stride 640 B, XOR-swizzled
  __shared__ u16 Bs[2][256 * 64];    // 64 KB
  const int tid = threadIdx.x;
  const int lane = tid & 63;
  const int w = tid >> 6;
  const int m0 = blockIdx.x << 6;

  auto stageB = [&](int buf, int kt){
    #pragma unroll
    for (int i = 0; i < 4; ++i){
      int cc = i * 512 + tid;
      int r2 = cc >> 3, s2 = cc & 7;
      gload16(WxhT + (size_t)r2 * 320 + kt * 64 + ((s2 ^ (r2 & 7)) << 3),
              &Bs[buf][cc * 8]);
    }
  };
  stageB(0, 0);   // fly under the mix phase

  // ---------------- mix phase ----------------
  for (int i = 0; i < 8; ++i){
    const int r = w * 8 + i;
    const int b = m0 + r;
    const u16* qrow = qb + (size_t)b * TDIM_;
    u16x8 q0 = *(const u16x8*)(qrow + lane * 8);
    u16x8 q1 = *(const u16x8*)(qrow + 512 + lane * 8);
    int idxm[MAXC_];
    #pragma unroll
    for (int m = 0; m < MAXC_; ++m) idxm[m] = rci[b * MAXC_ + m];
    float dots[MAXC_];
    #pragma unroll
    for (int m = 0; m < MAXC_; ++m){
      const u16* crow = cb + (size_t)idxm[m] * TDIM_;
      u16x8 c0 = *(const u16x8*)(crow + lane * 8);
      u16x8 c1 = *(const u16x8*)(crow + 512 + lane * 8);
      float s = 0.f;
      #pragma unroll
      for (int k = 0; k < 8; ++k) s += b2f(q0[k]) * b2f(c0[k]);
      #pragma unroll
      for (int k = 0; k < 8; ++k) s += b2f(q1[k]) * b2f(c1[k]);
      dots[m] = s;
    }
    #pragma unroll
    for (int o = 32; o; o >>= 1){
      #pragma unroll
      for (int m = 0; m < MAXC_; ++m) dots[m] += __shfl_xor(dots[m], o);
    }
    const float qnb = qn[b];
    float sv[MAXC_]; float mx = -3.0e38f;
    #pragma unroll
    for (int m = 0; m < MAXC_; ++m){
      float dnm = fmaxf(qnb * cn[idxm[m]], 1e-8f);
      float s = (filt[b * MAXC_ + m] == 0) ? -1e9f : dots[m] / dnm;
      sv[m] = s; mx = fmaxf(mx, s);
    }
    float se = 0.f;
    #pragma unroll
    for (int m = 0; m < MAXC_; ++m){ sv[m] = __expf(sv[m] - mx); se += sv[m]; }
    const float inv = 1.f / se;
    float rep = 0.f;
    #pragma unroll
    for (int m = 0; m < MAXC_; ++m) rep += sv[m] * redc[(size_t)idxm[m] * D_ + lane];
    rep *= inv;
    const float v0 = redq[(size_t)b * D_ + lane];
    const float hv = h[(size_t)b * D_ + lane];
    const float e0 = emb[(size_t)b * 128 + lane];
    const float e1 = emb[(size_t)b * 128 + 64 + lane];
    float p = hv * Wp[lane] + v0 * Wp[64 + lane] + rep * Wp[128 + lane]
            + e0 * Wp[192 + lane] + e1 * Wp[256 + lane];
    p = wsum(p);
    if (lane == 0) prob_out[b] = p + bp[0];
    const float o = op[b], om = 1.f - o;
    auto xst = [&](int col, float v){
      *(u16*)((char*)XH + r * 640 + ((col * 2) ^ ((r & 7) << 4))) = f2b(v);
    };
    xst(lane,        v0 * o  + e0 * om);
    xst(64 + lane,   rep * o + e1 * om);
    xst(128 + lane,  v0 * om + e0 * o);
    xst(192 + lane,  rep * om + e1 * o);
    xst(256 + lane,  hv);
  }
  LGKM0;          // xh ds_writes landed
  BAR();

  // ---------------- GRU GEMM phase ----------------
  const int lr = lane & 15, lq = lane >> 4;
  const int rf = w & 1, ch = w >> 1;
  f32x4 acc[2][4] = {};
  int cur = 0;
  for (int kt = 0; kt < 5; ++kt){
    if (kt < 4){ stageB(cur ^ 1, kt + 1); VMW(4); }
    else       { VMW(0); }
    BAR();
    #pragma unroll
    for (int ks = 0; ks < 2; ++ks){
      const int kb = ks * 64 + lq * 16;
      bf16x8 af[2], bfr[4];
      #pragma unroll
      for (int fr = 0; fr < 2; ++fr){
        int row = rf * 32 + fr * 16 + lr;
        af[fr] = *(const bf16x8*)((const char*)XH + row * 640 + ((kt * 128 + kb) ^ ((row & 7) << 4)));
      }
      #pragma unroll
      for (int fc = 0; fc < 4; ++fc){
        int row = ch * 64 + fc * 16 + lr;
        bfr[fc] = *(const bf16x8*)((const char*)Bs[cur] + row * 128 + (kb ^ ((row & 7) << 4)));
      }
      #pragma unroll
      for (int fr = 0; fr < 2; ++fr)
        #pragma unroll
        for (int fc = 0; fc < 4; ++fc)
          acc[fr][fc] = __builtin_amdgcn_mfma_f32_16x16x32_bf16(af[fr], bfr[fc],
                                                                acc[fr][fc], 0, 0, 0);
    }
    BAR();
    cur ^= 1;
  }
  const int d = ch * 16 + lr;
  float bg[4];
  #pragma unroll
  for (int g = 0; g < 4; ++g) bg[g] = bxh[ch * 64 + g * 16 + lr];
  #pragma unroll
  for (int fr = 0; fr < 2; ++fr){
    #pragma unroll
    for (int j = 0; j < 4; ++j){
      float rv = sigf(acc[fr][0][j] + bg[0]);
      float zv = sigf(acc[fr][1][j] + bg[1]);
      float nv = tanhf(acc[fr][2][j] + bg[2] + rv * (acc[fr][3][j] + bg[3]));
      int row = m0 + rf * 32 + fr * 16 + lq * 4 + j;
      float hv = h[(size_t)row * 64 + d];
      outh[(size_t)row * 64 + d] = (1.f - zv) * nv + zv * hv;
    }
  }
}

extern "C" void kernel_launch(void* const* d_in, const int* in_sizes, int n_in,
                              void* d_out, int out_size, void* d_ws, size_t ws_size,
                              hipStream_t stream) {
  const int*   prob_ids = (const int*)  d_in[0];
  const int*   rci      = (const int*)  d_in[1];
  const int*   filt     = (const int*)  d_in[2];
  const float* h        = (const float*)d_in[3];
  const float* emb      = (const float*)d_in[4];
  const float* op       = (const float*)d_in[5];
  const float* ex       = (const float*)d_in[6];
  const float* con      = (const float*)d_in[7];
  const float* W1       = (const float*)d_in[8];
  const float* b1       = (const float*)d_in[9];
  const float* W2       = (const float*)d_in[10];
  const float* b2       = (const float*)d_in[11];
  const float* Wp       = (const float*)d_in[12];
  const float* bp       = (const float*)d_in[13];
  const float* Wx       = (const float*)d_in[14];
  const float* Wh       = (const float*)d_in[15];
  const float* bx       = (const float*)d_in[16];
  const float* bh       = (const float*)d_in[17];
  float* out = (float*)d_out;

  char* w = (char*)d_ws;
  size_t off = 0;
  auto alloc = [&](size_t bytes){ size_t o = off; off = (off + bytes + 255) & ~(size_t)255; return o; };
  u16*   qb   = (u16*)  (w + alloc((size_t)B_ * TDIM_ * 2));      // 32 MB
  u16*   cb   = (u16*)  (w + alloc((size_t)NCONP_ * TDIM_ * 2));  // 4 MB
  float* qn   = (float*)(w + alloc((size_t)B_ * 4));
  float* cn   = (float*)(w + alloc((size_t)NCONP_ * 4));
  float* redq = (float*)(w + alloc((size_t)B_ * D_ * 4));         // 4 MB
  float* redc = (float*)(w + alloc((size_t)NCONP_ * D_ * 4));
  u16*   W1T  = (u16*)  (w + alloc((size_t)HID_ * TDIM_ * 2));
  u16*   W2T  = (u16*)  (w + alloc((size_t)D_ * HID_ * 2));
  u16*   WxhT = (u16*)  (w + alloc((size_t)256 * 320 * 2));
  float* bxh  = (float*)(w + alloc((size_t)256 * 4));

  k_prep<<<6017, 256, 0, stream>>>(ex, prob_ids, con, W1, W2, Wx, Wh, bx, bh,
                                   qb, qn, cb, cn, W1T, W2T, WxhT, bxh);
  k_mlp<<<288, 512, 0, stream>>>(qb, cb, W1T, b1, W2T, b2, redq, redc);
  k_mixgru<<<256, 512, 0, stream>>>(qb, cb, qn, cn, rci, filt, redq, redc,
                                    h, emb, op, Wp, bp, WxhT, bxh, out, out + B_);
}

// Round 4
// 109.849 us; speedup vs baseline: 1.0767x; 1.0038x over previous
//
#include <hip/hip_runtime.h>
#include <cstdint>
#include <cstddef>

typedef unsigned short u16;
typedef __bf16 bf16x8 __attribute__((ext_vector_type(8)));
typedef float f32x4 __attribute__((ext_vector_type(4)));
typedef u16 u16x4 __attribute__((ext_vector_type(4)));
typedef u16 u16x8 __attribute__((ext_vector_type(8)));

#define B_ 16384
#define D_ 64
#define MAXC_ 8
#define NCON_ 2000
#define NCONP_ 2048
#define TDIM_ 1024
#define HID_ 256

#define VMW(n) asm volatile("s_waitcnt vmcnt(" #n ")" ::: "memory")
#define LGKM0 asm volatile("s_waitcnt lgkmcnt(0)" ::: "memory")
#define BAR() __builtin_amdgcn_s_barrier()

__device__ inline u16 f2b(float f){
  unsigned u = __float_as_uint(f);
  u += 0x7fffu + ((u >> 16) & 1u);
  return (u16)(u >> 16);
}
__device__ inline float b2f(u16 u){ return __uint_as_float(((unsigned)u) << 16); }

__device__ inline void gload16(const void* g, void* l){
  __builtin_amdgcn_global_load_lds((const __attribute__((address_space(1))) unsigned*)g,
                                   (__attribute__((address_space(3))) unsigned*)l, 16, 0, 0);
}

__device__ inline float wsum(float v){
  #pragma unroll
  for (int o = 32; o; o >>= 1) v += __shfl_xor(v, o);
  return v;
}
__device__ inline float sigf(float x){ return 1.f / (1.f + __expf(-x)); }

// =================== k_prep: concepts + weight prep =========================
// grid sections: [0,512) concepts, [512,1921) weights
__global__ __launch_bounds__(256) void k_prep(
    const float* __restrict__ con,
    const float* __restrict__ W1, const float* __restrict__ W2,
    const float* __restrict__ Wx, const float* __restrict__ Wh,
    const float* __restrict__ bx, const float* __restrict__ bh,
    u16* __restrict__ cb, float* __restrict__ cn,
    u16* __restrict__ W1T, u16* __restrict__ W2T, u16* __restrict__ WxhT,
    float* __restrict__ bxh)
{
  const int bid = blockIdx.x, tid = threadIdx.x;
  const int lane = tid & 63;
  if (bid < 512){                                   // ---- concepts ----
    const int r = bid * 4 + (tid >> 6);
    u16* dst = cb + (size_t)r * TDIM_;
    if (r < NCON_){
      const float* src = con + (size_t)r * TDIM_;
      float ss = 0.f;
      #pragma unroll
      for (int c = 0; c < 4; ++c){
        float4 v = *(const float4*)(src + c * 256 + lane * 4);
        ss += v.x*v.x + v.y*v.y + v.z*v.z + v.w*v.w;
        u16x4 o = { f2b(v.x), f2b(v.y), f2b(v.z), f2b(v.w) };
        *(u16x4*)(dst + c * 256 + lane * 4) = o;
      }
      ss = wsum(ss);
      if (lane == 0) cn[r] = sqrtf(ss);
    } else {
      u16x4 z = { 0, 0, 0, 0 };
      #pragma unroll
      for (int c = 0; c < 4; ++c) *(u16x4*)(dst + c * 256 + lane * 4) = z;
    }
  } else {                                          // ---- weights ----
    int gid = (bid - 512) * 256 + tid;
    if (gid < 262144){                       // W1T: n*1024 + k
      int n = gid >> 10, k = gid & 1023;
      W1T[gid] = f2b(W1[(size_t)k * 256 + n]);
    } else if (gid < 278528){                // W2T: n*256 + k
      int t = gid - 262144;
      int n = t >> 8, k = t & 255;
      W2T[t] = f2b(W2[(size_t)k * 64 + n]);
    } else if (gid < 360448){                // WxhT: c*320 + k, gate-interleaved
      int t = gid - 278528;
      int c = t / 320, k = t % 320;
      int g = (c >> 4) & 3;
      int d = (c >> 6) * 16 + (c & 15);
      float v = 0.f;
      if (k < 256){
        if (g == 0)      v = Wx[(size_t)k * 192 + d];
        else if (g == 1) v = Wx[(size_t)k * 192 + 64 + d];
        else if (g == 2) v = Wx[(size_t)k * 192 + 128 + d];
      } else {
        int kh = k - 256;
        if (g == 0)      v = Wh[(size_t)kh * 192 + d];
        else if (g == 1) v = Wh[(size_t)kh * 192 + 64 + d];
        else if (g == 3) v = Wh[(size_t)kh * 192 + 128 + d];
      }
      WxhT[t] = f2b(v);
    } else if (gid < 360704){                // bxh
      int c = gid - 360448;
      int g = (c >> 4) & 3;
      int d = (c >> 6) * 16 + (c & 15);
      float v;
      if (g == 0)      v = bx[d] + bh[d];
      else if (g == 1) v = bx[64 + d] + bh[64 + d];
      else if (g == 2) v = bx[128 + d];
      else             v = bh[128 + d];
      bxh[c] = v;
    }
  }
}

// =================== k_mlp: gather + relu(A@W1+b1)@W2+b2 ====================
// blocks [0,256): q-side (A reg-gathered from ex, also writes qb+qn),
// blocks [256,288): c-side (A from cb). BM=64, BN=256, 512 thr / 8 waves.
// LDS 72 KB -> 2 blocks/CU.
__global__ __launch_bounds__(512, 4) void k_mlp(
    const float* __restrict__ ex, const int* __restrict__ pid,
    const u16* __restrict__ cb, const u16* __restrict__ W1T,
    const float* __restrict__ b1, const u16* __restrict__ W2T,
    const float* __restrict__ b2, u16* __restrict__ qb,
    float* __restrict__ qn, float* __restrict__ redq,
    float* __restrict__ redc)
{
  __shared__ u16 As[64 * 64];      // 8 KB (single buffer)
  __shared__ u16 Bs[256 * 64];     // 32 KB (single buffer)
  __shared__ u16 Hs[64 * 256];     // 32 KB
  const int tid = threadIdx.x;
  const int lane = tid & 63;
  const int w = tid >> 6;
  const int lr = lane & 15, lq = lane >> 4;
  const bool qside = blockIdx.x < 256;
  const int m0 = qside ? ((int)blockIdx.x << 6) : (((int)blockIdx.x - 256) << 6);
  const int row = tid >> 3;                    // LDS A row this thread stages
  const int subp = (tid & 7) ^ (row & 7);      // pre-swizzled source chunk
  const int e0 = subp * 8;                     // element offset in 64-col tile
  const float* arow_f = nullptr;
  const u16*   arow_b = nullptr;
  if (qside) arow_f = ex + (size_t)pid[m0 + row] * TDIM_;
  else       arow_b = cb + (size_t)(m0 + row) * TDIM_;

  const int rf = w & 1, ch = w >> 1;
  f32x4 acc[2][4] = {};
  float ss = 0.f;
  float4 a0, a1; u16x8 cr;
  if (qside){ a0 = *(const float4*)(arow_f + e0); a1 = *(const float4*)(arow_f + e0 + 4); }
  else      { cr = *(const u16x8*)(arow_b + e0); }

  for (int kt = 0; kt < 16; ++kt){
    u16x8 r;
    if (qside){
      r[0]=f2b(a0.x); r[1]=f2b(a0.y); r[2]=f2b(a0.z); r[3]=f2b(a0.w);
      r[4]=f2b(a1.x); r[5]=f2b(a1.y); r[6]=f2b(a1.z); r[7]=f2b(a1.w);
      ss += a0.x*a0.x + a0.y*a0.y + a0.z*a0.z + a0.w*a0.w
          + a1.x*a1.x + a1.y*a1.y + a1.z*a1.z + a1.w*a1.w;
      *(u16x8*)(qb + (size_t)(m0 + row) * TDIM_ + kt * 64 + e0) = r;
    } else r = cr;
    *(u16x8*)(As + tid * 8) = r;               // linear LDS, source pre-swizzled
    #pragma unroll
    for (int i = 0; i < 4; ++i){
      int cc = i * 512 + tid;
      int r2 = cc >> 3, s2 = cc & 7;
      gload16(W1T + (size_t)r2 * 1024 + kt * 64 + ((s2 ^ (r2 & 7)) << 3), &Bs[cc * 8]);
    }
    if (kt < 15){
      int e = (kt + 1) * 64 + e0;
      if (qside){
        a0 = *(const float4*)(arow_f + e); a1 = *(const float4*)(arow_f + e + 4);
        VMW(2);                                // drain store+4 B-gloads; A stays in flight
      } else {
        cr = *(const u16x8*)(arow_b + e);
        VMW(1);                                // drain 4 B-gloads; A stays in flight
      }
    } else VMW(0);
    LGKM0;
    BAR();
    #pragma unroll
    for (int ks = 0; ks < 2; ++ks){
      const int kb = ks * 64 + lq * 16;
      bf16x8 af[2], bfr[4];
      #pragma unroll
      for (int fr = 0; fr < 2; ++fr){
        int rr = rf * 32 + fr * 16 + lr;
        af[fr] = *(const bf16x8*)((const char*)As + rr * 128 + (kb ^ ((rr & 7) << 4)));
      }
      #pragma unroll
      for (int fc = 0; fc < 4; ++fc){
        int rr = ch * 64 + fc * 16 + lr;
        bfr[fc] = *(const bf16x8*)((const char*)Bs + rr * 128 + (kb ^ ((rr & 7) << 4)));
      }
      #pragma unroll
      for (int fr = 0; fr < 2; ++fr)
        #pragma unroll
        for (int fc = 0; fc < 4; ++fc)
          acc[fr][fc] = __builtin_amdgcn_mfma_f32_16x16x32_bf16(af[fr], bfr[fc],
                                                                acc[fr][fc], 0, 0, 0);
    }
    BAR();
  }
  if (qside){
    ss += __shfl_xor(ss, 1); ss += __shfl_xor(ss, 2); ss += __shfl_xor(ss, 4);
    if ((tid & 7) == 0) qn[m0 + row] = sqrtf(ss);
  }
  // hidden -> LDS (bias + relu + bf16), swizzled
  #pragma unroll
  for (int fr = 0; fr < 2; ++fr)
    #pragma unroll
    for (int fc = 0; fc < 4; ++fc){
      int col = ch * 64 + fc * 16 + lr;
      float bv = b1[col];
      #pragma unroll
      for (int j = 0; j < 4; ++j){
        int rr = rf * 32 + fr * 16 + lq * 4 + j;
        float v = fmaxf(acc[fr][fc][j] + bv, 0.f);
        *(u16*)((char*)Hs + rr * 512 + ((col * 2) ^ ((rr & 7) << 4))) = f2b(v);
      }
    }
  __syncthreads();
  // layer 2: [64,256] @ W2T[64,256]^T (w2f loaded late to fit 128 VGPR)
  const int rf2 = w & 3, cp = w >> 2;
  bf16x8 w2f[8][2];
  #pragma unroll
  for (int ks2 = 0; ks2 < 8; ++ks2)
    #pragma unroll
    for (int t = 0; t < 2; ++t){
      int row64 = (cp * 2 + t) * 16 + lr;
      w2f[ks2][t] = *(const bf16x8*)(W2T + (size_t)row64 * 256 + ks2 * 32 + lq * 8);
    }
  f32x4 acc2[2] = {};
  #pragma unroll
  for (int ks2 = 0; ks2 < 8; ++ks2){
    int rr = rf2 * 16 + lr;
    int kb2 = ks2 * 64 + lq * 16;
    bf16x8 af2 = *(const bf16x8*)((const char*)Hs + rr * 512 + (kb2 ^ ((rr & 7) << 4)));
    #pragma unroll
    for (int t = 0; t < 2; ++t)
      acc2[t] = __builtin_amdgcn_mfma_f32_16x16x32_bf16(af2, w2f[ks2][t], acc2[t], 0, 0, 0);
  }
  float* Obase = qside ? redq : redc;
  #pragma unroll
  for (int t = 0; t < 2; ++t){
    int col = (cp * 2 + t) * 16 + lr;
    float bv = b2[col];
    #pragma unroll
    for (int j = 0; j < 4; ++j){
      int rr = m0 + rf2 * 16 + lq * 4 + j;
      Obase[(size_t)rr * 64 + col] = acc2[t][j] + bv;
    }
  }
}

// =================== k_mixgru: cosine/softmax/pred + GRU GEMM ===============
// 256 blocks x 512 thr, LDS 72 KB -> 2 blocks/CU. xh lives in LDS only.
__global__ __launch_bounds__(512, 4) void k_mixgru(
    const u16* __restrict__ qb, const u16* __restrict__ cb,
    const float* __restrict__ qn, const float* __restrict__ cn,
    const int* __restrict__ rci, const int* __restrict__ filt,
    const float* __restrict__ redq, const float* __restrict__ redc,
    const float* __restrict__ h, const float* __restrict__ emb,
    const float* __restrict__ op, const float* __restrict__ Wp,
    const float* __restrict__ bp, const u16* __restrict__ WxhT,
    const float* __restrict__ bxh, float* __restrict__ prob_out,
    float* __restrict__ outh)
{
  __shared__ u16 XH[64 * 320];     // 40 KB, row stride 640 B, XOR-swizzled
  __shared__ u16 Bs[256 * 64];     // 32 KB (single buffer)
  const int tid = threadIdx.x;
  const int lane = tid & 63;
  const int w = tid >> 6;
  const int m0 = blockIdx.x << 6;

  auto stageB = [&](int kt){
    #pragma unroll
    for (int i = 0; i < 4; ++i){
      int cc = i * 512 + tid;
      int r2 = cc >> 3, s2 = cc & 7;
      gload16(WxhT + (size_t)r2 * 320 + kt * 64 + ((s2 ^ (r2 & 7)) << 3), &Bs[cc * 8]);
    }
  };
  stageB(0);   // flies under the mix phase

  // ---------------- mix phase ----------------
  for (int i = 0; i < 8; ++i){
    const int r = w * 8 + i;
    const int b = m0 + r;
    const u16* qrow = qb + (size_t)b * TDIM_;
    u16x8 q0 = *(const u16x8*)(qrow + lane * 8);
    u16x8 q1 = *(const u16x8*)(qrow + 512 + lane * 8);
    int idxm[MAXC_];
    #pragma unroll
    for (int m = 0; m < MAXC_; ++m) idxm[m] = rci[b * MAXC_ + m];
    float dots[MAXC_];
    #pragma unroll
    for (int m = 0; m < MAXC_; ++m){
      const u16* crow = cb + (size_t)idxm[m] * TDIM_;
      u16x8 c0 = *(const u16x8*)(crow + lane * 8);
      u16x8 c1 = *(const u16x8*)(crow + 512 + lane * 8);
      float s = 0.f;
      #pragma unroll
      for (int k = 0; k < 8; ++k) s += b2f(q0[k]) * b2f(c0[k]);
      #pragma unroll
      for (int k = 0; k < 8; ++k) s += b2f(q1[k]) * b2f(c1[k]);
      dots[m] = s;
    }
    #pragma unroll
    for (int o = 32; o; o >>= 1){
      #pragma unroll
      for (int m = 0; m < MAXC_; ++m) dots[m] += __shfl_xor(dots[m], o);
    }
    const float qnb = qn[b];
    float sv[MAXC_]; float mx = -3.0e38f;
    #pragma unroll
    for (int m = 0; m < MAXC_; ++m){
      float dnm = fmaxf(qnb * cn[idxm[m]], 1e-8f);
      float s = (filt[b * MAXC_ + m] == 0) ? -1e9f : dots[m] / dnm;
      sv[m] = s; mx = fmaxf(mx, s);
    }
    float se = 0.f;
    #pragma unroll
    for (int m = 0; m < MAXC_; ++m){ sv[m] = __expf(sv[m] - mx); se += sv[m]; }
    const float inv = 1.f / se;
    float rep = 0.f;
    #pragma unroll
    for (int m = 0; m < MAXC_; ++m) rep += sv[m] * redc[(size_t)idxm[m] * D_ + lane];
    rep *= inv;
    const float v0 = redq[(size_t)b * D_ + lane];
    const float hv = h[(size_t)b * D_ + lane];
    const float e0 = emb[(size_t)b * 128 + lane];
    const float e1 = emb[(size_t)b * 128 + 64 + lane];
    float p = hv * Wp[lane] + v0 * Wp[64 + lane] + rep * Wp[128 + lane]
            + e0 * Wp[192 + lane] + e1 * Wp[256 + lane];
    p = wsum(p);
    if (lane == 0) prob_out[b] = p + bp[0];
    const float o = op[b], om = 1.f - o;
    auto xst = [&](int col, float v){
      *(u16*)((char*)XH + r * 640 + ((col * 2) ^ ((r & 7) << 4))) = f2b(v);
    };
    xst(lane,        v0 * o  + e0 * om);
    xst(64 + lane,   rep * o + e1 * om);
    xst(128 + lane,  v0 * om + e0 * o);
    xst(192 + lane,  rep * om + e1 * o);
    xst(256 + lane,  hv);
  }
  LGKM0;          // xh ds_writes landed

  // ---------------- GRU GEMM phase ----------------
  const int lr = lane & 15, lq = lane >> 4;
  const int rf = w & 1, ch = w >> 1;
  f32x4 acc[2][4] = {};
  for (int kt = 0; kt < 5; ++kt){
    VMW(0);                      // B[kt] landed
    BAR();
    #pragma unroll
    for (int ks = 0; ks < 2; ++ks){
      const int kb = ks * 64 + lq * 16;
      bf16x8 af[2], bfr[4];
      #pragma unroll
      for (int fr = 0; fr < 2; ++fr){
        int rr = rf * 32 + fr * 16 + lr;
        af[fr] = *(const bf16x8*)((const char*)XH + rr * 640 + ((kt * 128 + kb) ^ ((rr & 7) << 4)));
      }
      #pragma unroll
      for (int fc = 0; fc < 4; ++fc){
        int rr = ch * 64 + fc * 16 + lr;
        bfr[fc] = *(const bf16x8*)((const char*)Bs + rr * 128 + (kb ^ ((rr & 7) << 4)));
      }
      #pragma unroll
      for (int fr = 0; fr < 2; ++fr)
        #pragma unroll
        for (int fc = 0; fc < 4; ++fc)
          acc[fr][fc] = __builtin_amdgcn_mfma_f32_16x16x32_bf16(af[fr], bfr[fc],
                                                                acc[fr][fc], 0, 0, 0);
    }
    BAR();
    if (kt < 4) stageB(kt + 1);  // safe: all waves past readers' barrier
  }
  const int d = ch * 16 + lr;
  float bg[4];
  #pragma unroll
  for (int g = 0; g < 4; ++g) bg[g] = bxh[ch * 64 + g * 16 + lr];
  #pragma unroll
  for (int fr = 0; fr < 2; ++fr){
    #pragma unroll
    for (int j = 0; j < 4; ++j){
      float rv = sigf(acc[fr][0][j] + bg[0]);
      float zv = sigf(acc[fr][1][j] + bg[1]);
      float nv = tanhf(acc[fr][2][j] + bg[2] + rv * (acc[fr][3][j] + bg[3]));
      int rr = m0 + rf * 32 + fr * 16 + lq * 4 + j;
      float hv = h[(size_t)rr * 64 + d];
      outh[(size_t)rr * 64 + d] = (1.f - zv) * nv + zv * hv;
    }
  }
}

extern "C" void kernel_launch(void* const* d_in, const int* in_sizes, int n_in,
                              void* d_out, int out_size, void* d_ws, size_t ws_size,
                              hipStream_t stream) {
  const int*   prob_ids = (const int*)  d_in[0];
  const int*   rci      = (const int*)  d_in[1];
  const int*   filt     = (const int*)  d_in[2];
  const float* h        = (const float*)d_in[3];
  const float* emb      = (const float*)d_in[4];
  const float* op       = (const float*)d_in[5];
  const float* ex       = (const float*)d_in[6];
  const float* con      = (const float*)d_in[7];
  const float* W1       = (const float*)d_in[8];
  const float* b1       = (const float*)d_in[9];
  const float* W2       = (const float*)d_in[10];
  const float* b2       = (const float*)d_in[11];
  const float* Wp       = (const float*)d_in[12];
  const float* bp       = (const float*)d_in[13];
  const float* Wx       = (const float*)d_in[14];
  const float* Wh       = (const float*)d_in[15];
  const float* bx       = (const float*)d_in[16];
  const float* bh       = (const float*)d_in[17];
  float* out = (float*)d_out;

  char* w = (char*)d_ws;
  size_t off = 0;
  auto alloc = [&](size_t bytes){ size_t o = off; off = (off + bytes + 255) & ~(size_t)255; return o; };
  u16*   qb   = (u16*)  (w + alloc((size_t)B_ * TDIM_ * 2));      // 32 MB
  u16*   cb   = (u16*)  (w + alloc((size_t)NCONP_ * TDIM_ * 2));  // 4 MB
  float* qn   = (float*)(w + alloc((size_t)B_ * 4));
  float* cn   = (float*)(w + alloc((size_t)NCONP_ * 4));
  float* redq = (float*)(w + alloc((size_t)B_ * D_ * 4));         // 4 MB
  float* redc = (float*)(w + alloc((size_t)NCONP_ * D_ * 4));
  u16*   W1T  = (u16*)  (w + alloc((size_t)HID_ * TDIM_ * 2));
  u16*   W2T  = (u16*)  (w + alloc((size_t)D_ * HID_ * 2));
  u16*   WxhT = (u16*)  (w + alloc((size_t)256 * 320 * 2));
  float* bxh  = (float*)(w + alloc((size_t)256 * 4));

  k_prep<<<1921, 256, 0, stream>>>(con, W1, W2, Wx, Wh, bx, bh,
                                   cb, cn, W1T, W2T, WxhT, bxh);
  k_mlp<<<288, 512, 0, stream>>>(ex, prob_ids, cb, W1T, b1, W2T, b2,
                                 qb, qn, redq, redc);
  k_mixgru<<<256, 512, 0, stream>>>(qb, cb, qn, cn, rci, filt, redq, redc,
                                    h, emb, op, Wp, bp, WxhT, bxh, out, out + B_);
}